// Round 1
// baseline (1075.632 us; speedup 1.0000x reference)
//
#include <hip/hip_runtime.h>
#include <math.h>

// ---------------------------------------------------------------------------
// PhaseBiasedCrossAttention, MI355X/gfx950.
// Pipeline: [tab] fp64 cos/sin tables -> [proj] QKV projections (hi/lo bf16
// split GEMM, MFMA 16x16x32) -> [attn] per-(b,h,16q) workgroup: QK^T (hi/lo)
// + rank-2 phase bias + register-resident softmax + attn write + PV ->
// [oproj] output projection (plain bf16 GEMM).
// Scratch layout (d_ws): Qh Ql Kh Kl Vt heads (6 x 8MiB bf16) + ctab/stab.
// ---------------------------------------------------------------------------

#define DEV __device__ __forceinline__

using f32x4 = __attribute__((ext_vector_type(4))) float;
using s16x8 = __attribute__((ext_vector_type(8))) short;
using s16x4 = __attribute__((ext_vector_type(4))) short;

constexpr int NB_ = 4;     // batch
constexpr int NH_ = 8;     // heads
constexpr int L_  = 2048;  // seq len (Lq == Lk)
constexpr int DM_ = 512;   // d_model
constexpr int DK_ = 64;    // head dim

DEV short f2bf(float f) {                 // fp32 -> bf16 (RNE), no NaNs here
  unsigned u = __float_as_uint(f);
  u += 0x7fffu + ((u >> 16) & 1u);
  return (short)(u >> 16);
}
DEV float bf2f(short s) {
  return __uint_as_float((unsigned)(unsigned short)s << 16);
}
DEV f32x4 mfma16(s16x8 a, s16x8 b, f32x4 c) {
  return __builtin_amdgcn_mfma_f32_16x16x32_bf16(a, b, c, 0, 0, 0);
}
DEV void split8(const float* f, s16x8& hi, s16x8& lo) {
#pragma unroll
  for (int j = 0; j < 8; ++j) {
    short h = f2bf(f[j]);
    hi[j] = h;
    lo[j] = f2bf(f[j] - bf2f(h));
  }
}

// --------------------------- cos/sin tables --------------------------------
__global__ void tab_kernel(const float* __restrict__ log_omega,
                           float* __restrict__ ctab, float* __restrict__ stab) {
  int h = blockIdx.y;
  int t = blockIdx.x * 256 + threadIdx.x;
  float om = expf(log_omega[h]);                    // matches ref fp32 exp
  double a = 6.283185307179586 * (double)om * (double)t;
  ctab[h * L_ + t] = (float)cos(a);
  stab[h * L_ + t] = (float)sin(a);
}

// ------------------- QKV projection GEMM (hi/lo split) ---------------------
// C[m,n] = X[m,:] . W[n,:] + b[n];  z=0 -> Q (scaled by 1/8, hi/lo out),
// z=1 -> K (hi/lo out), z=2 -> V (bf16, transposed [b,h,d,l]).
__global__ __launch_bounds__(256, 2)
void proj_kernel(const float* __restrict__ Qin, const float* __restrict__ Kin,
                 const float* __restrict__ Vin,
                 const float* __restrict__ Wq, const float* __restrict__ bq,
                 const float* __restrict__ Wk, const float* __restrict__ bk,
                 const float* __restrict__ Wv, const float* __restrict__ bv,
                 short* __restrict__ Qh, short* __restrict__ Ql,
                 short* __restrict__ Kh, short* __restrict__ Kl,
                 short* __restrict__ Vt) {
  __shared__ short Ash[128 * 32], Asl[128 * 32], Bsh[128 * 32], Bsl[128 * 32];
  const int z = blockIdx.z;
  const float* X = (z == 0) ? Qin : (z == 1) ? Kin : Vin;
  const float* W = (z == 0) ? Wq : (z == 1) ? Wk : Wv;
  const float* bias = (z == 0) ? bq : (z == 1) ? bk : bv;
  const int m0 = blockIdx.x * 128, n0 = blockIdx.y * 128;
  const int t = threadIdx.x, lane = t & 63, w = t >> 6;
  const int wr = w >> 1, wc = w & 1;
  const int fr = lane & 15, fg = lane >> 4;

  f32x4 acc[4][4];
#pragma unroll
  for (int a = 0; a < 4; ++a)
#pragma unroll
    for (int b = 0; b < 4; ++b) acc[a][b] = f32x4{0.f, 0.f, 0.f, 0.f};

  for (int kt = 0; kt < 16; ++kt) {
    __syncthreads();
#pragma unroll
    for (int cc = 0; cc < 2; ++cc) {
      int cid = t + cc * 256;                 // chunk id over [128 rows][4 kblk]
      int row = cid >> 2, kb = cid & 3;
      float fa[8], fb[8];
      const float* ga = X + (size_t)(m0 + row) * DM_ + kt * 32 + kb * 8;
      const float* gb = W + (size_t)(n0 + row) * DM_ + kt * 32 + kb * 8;
      *(f32x4*)&fa[0] = *(const f32x4*)ga;  *(f32x4*)&fa[4] = *(const f32x4*)(ga + 4);
      *(f32x4*)&fb[0] = *(const f32x4*)gb;  *(f32x4*)&fb[4] = *(const f32x4*)(gb + 4);
      s16x8 hi, lo;
      split8(fa, hi, lo);
      ((s16x8*)Ash)[cid] = hi; ((s16x8*)Asl)[cid] = lo;
      split8(fb, hi, lo);
      ((s16x8*)Bsh)[cid] = hi; ((s16x8*)Bsl)[cid] = lo;
    }
    __syncthreads();
    s16x8 ah[4], al[4], bh_[4], bl_[4];
#pragma unroll
    for (int fm = 0; fm < 4; ++fm) {
      int r = wr * 64 + fm * 16 + fr;
      ah[fm] = ((const s16x8*)Ash)[r * 4 + fg];
      al[fm] = ((const s16x8*)Asl)[r * 4 + fg];
    }
#pragma unroll
    for (int fn = 0; fn < 4; ++fn) {
      int r = wc * 64 + fn * 16 + fr;
      bh_[fn] = ((const s16x8*)Bsh)[r * 4 + fg];
      bl_[fn] = ((const s16x8*)Bsl)[r * 4 + fg];
    }
#pragma unroll
    for (int fm = 0; fm < 4; ++fm)
#pragma unroll
      for (int fn = 0; fn < 4; ++fn) {
        acc[fm][fn] = mfma16(ah[fm], bh_[fn], acc[fm][fn]);
        acc[fm][fn] = mfma16(ah[fm], bl_[fn], acc[fm][fn]);
        acc[fm][fn] = mfma16(al[fm], bh_[fn], acc[fm][fn]);
      }
  }

  const float scale = (z == 0) ? 0.125f : 1.0f;   // fold 1/sqrt(DK) into Q
#pragma unroll
  for (int fn = 0; fn < 4; ++fn) {
    int C = n0 + wc * 64 + fn * 16 + fr;
    float bb = bias[C];
    int hh = C >> 6, d = C & 63;
#pragma unroll
    for (int fm = 0; fm < 4; ++fm) {
      int Rbase = m0 + wr * 64 + fm * 16 + fg * 4;
      if (z < 2) {
        short* Dh = (z == 0) ? Qh : Kh;
        short* Dl = (z == 0) ? Ql : Kl;
#pragma unroll
        for (int i = 0; i < 4; ++i) {
          int R = Rbase + i;
          int b = R >> 11, lq = R & 2047;
          float v = (acc[fm][fn][i] + bb) * scale;
          short h16 = f2bf(v);
          size_t off = ((size_t)(b * NH_ + hh) * L_ + lq) * DK_ + d;
          Dh[off] = h16;
          Dl[off] = f2bf(v - bf2f(h16));
        }
      } else {  // V: transposed [b,h,d,l], 4 consecutive l -> 8B packed store
        s16x4 p;
#pragma unroll
        for (int i = 0; i < 4; ++i) p[i] = f2bf(acc[fm][fn][i] + bb);
        int b = Rbase >> 11, lq = Rbase & 2047;
        size_t off = ((size_t)(b * NH_ + hh) * DK_ + d) * L_ + lq;
        *(s16x4*)(Vt + off) = p;
      }
    }
  }
}

// ------------------------------ attention ----------------------------------
// One WG = (b,h) x 16 q-rows; 8 waves x 256-k slice. S kept in registers.
__global__ __launch_bounds__(512, 1)
void attn_kernel(const short* __restrict__ Qh, const short* __restrict__ Ql,
                 const short* __restrict__ Kh, const short* __restrict__ Kl,
                 const short* __restrict__ Vt,
                 const float* __restrict__ ctab, const float* __restrict__ stab,
                 float* __restrict__ attn, short* __restrict__ heads) {
  __shared__ short P[16 * 2048];                 // 64 KiB; stats overlaid first
  const int bh = blockIdx.y, q0 = blockIdx.x * 16;
  const int b = bh >> 3, h = bh & 7;
  const int tid = threadIdx.x, w = tid >> 6, lane = tid & 63;
  const int fr = lane & 15, fg = lane >> 4;
  const int wk0 = w * 256;

  // Q fragments (A operand): row = q0+fr, k(=d) = fg*8 + 32*c
  size_t qoff = ((size_t)bh * L_ + q0 + fr) * DK_ + fg * 8;
  s16x8 qh0 = *(const s16x8*)(Qh + qoff), qh1 = *(const s16x8*)(Qh + qoff + 32);
  s16x8 ql0 = *(const s16x8*)(Ql + qoff), ql1 = *(const s16x8*)(Ql + qoff + 32);
  float cq[4], sq[4];
#pragma unroll
  for (int i = 0; i < 4; ++i) {
    cq[i] = ctab[h * L_ + q0 + fg * 4 + i];
    sq[i] = stab[h * L_ + q0 + fg * 4 + i];
  }

  // ---- pass 1: S = (Q.K)/8 + phase bias, fully register-resident ----
  f32x4 S[16];
#pragma unroll
  for (int t = 0; t < 16; ++t) {
    int kr = wk0 + t * 16 + fr;
    size_t koff = ((size_t)bh * L_ + kr) * DK_ + fg * 8;
    s16x8 kh0 = *(const s16x8*)(Kh + koff), kh1 = *(const s16x8*)(Kh + koff + 32);
    s16x8 kl0 = *(const s16x8*)(Kl + koff), kl1 = *(const s16x8*)(Kl + koff + 32);
    float ck = ctab[h * L_ + kr], sk = stab[h * L_ + kr];
    f32x4 c = f32x4{0.f, 0.f, 0.f, 0.f};
    c = mfma16(qh0, kh0, c); c = mfma16(qh1, kh1, c);   // hi*hi
    c = mfma16(qh0, kl0, c); c = mfma16(qh1, kl1, c);   // hi*lo
    c = mfma16(ql0, kh0, c); c = mfma16(ql1, kh1, c);   // lo*hi
#pragma unroll
    for (int i = 0; i < 4; ++i) c[i] += cq[i] * ck + sq[i] * sk;
    S[t] = c;
  }

  // ---- softmax stats: rows live on 16-lane groups; butterfly + LDS merge ----
  float m[4];
#pragma unroll
  for (int i = 0; i < 4; ++i) m[i] = -1e30f;
#pragma unroll
  for (int t = 0; t < 16; ++t)
#pragma unroll
    for (int i = 0; i < 4; ++i) m[i] = fmaxf(m[i], S[t][i]);
#pragma unroll
  for (int d = 1; d < 16; d <<= 1)
#pragma unroll
    for (int i = 0; i < 4; ++i) m[i] = fmaxf(m[i], __shfl_xor(m[i], d));
  float* sm = (float*)P;        // [16 rows][8 waves]
  float* ss = sm + 128;
  if (fr == 0)
#pragma unroll
    for (int i = 0; i < 4; ++i) sm[(fg * 4 + i) * 8 + w] = m[i];
  __syncthreads();
  float gm[4], sum[4] = {0.f, 0.f, 0.f, 0.f};
#pragma unroll
  for (int i = 0; i < 4; ++i) {
    float mm = -1e30f;
#pragma unroll
    for (int ww = 0; ww < 8; ++ww) mm = fmaxf(mm, sm[(fg * 4 + i) * 8 + ww]);
    gm[i] = mm;
  }
#pragma unroll
  for (int t = 0; t < 16; ++t)
#pragma unroll
    for (int i = 0; i < 4; ++i) {
      float e = __expf(S[t][i] - gm[i]);
      S[t][i] = e;
      sum[i] += e;
    }
#pragma unroll
  for (int d = 1; d < 16; d <<= 1)
#pragma unroll
    for (int i = 0; i < 4; ++i) sum[i] += __shfl_xor(sum[i], d);
  if (fr == 0)
#pragma unroll
    for (int i = 0; i < 4; ++i) ss[(fg * 4 + i) * 8 + w] = sum[i];
  __syncthreads();
  float invl[4];
#pragma unroll
  for (int i = 0; i < 4; ++i) {
    float s_ = 0.f;
#pragma unroll
    for (int ww = 0; ww < 8; ++ww) s_ += ss[(fg * 4 + i) * 8 + ww];
    invl[i] = 1.0f / s_;
  }
  __syncthreads();  // stats consumed; P region may now be overwritten

  // ---- pass 2: write attn (fp32, HBM floor) + P (bf16, XOR-swizzled LDS) ----
#pragma unroll
  for (int t = 0; t < 16; ++t) {
    int col = wk0 + t * 16 + fr;
#pragma unroll
    for (int i = 0; i < 4; ++i) {
      int row = fg * 4 + i;
      float p = S[t][i] * invl[i];
      attn[((size_t)bh * L_ + q0 + row) * L_ + col] = p;
      int chunk = (col >> 3) ^ (row & 7);           // G4 bank-conflict swizzle
      P[row * 2048 + chunk * 8 + (col & 7)] = f2bf(p);
    }
  }
  __syncthreads();

  // ---- pass 3: PV. Waves 0..3, 16 d-cols each, full k; V^T streamed from L2.
  if (w < 4) {
    int d0 = w * 16;
    f32x4 o = f32x4{0.f, 0.f, 0.f, 0.f};
    size_t vbase = ((size_t)bh * DK_ + d0 + fr) * L_;
#pragma unroll 4
    for (int kt = 0; kt < 64; ++kt) {
      int swz = (kt * 4 + fg) ^ (fr & 7);
      s16x8 a = *(const s16x8*)&P[fr * 2048 + swz * 8];
      s16x8 vb = *(const s16x8*)(Vt + vbase + kt * 32 + fg * 8);
      o = mfma16(a, vb, o);
    }
#pragma unroll
    for (int i = 0; i < 4; ++i) {
      int R = q0 + fg * 4 + i;
      heads[((size_t)b * L_ + R) * DM_ + h * DK_ + d0 + fr] = f2bf(o[i]);
    }
  }
}

// ------------------------ output projection GEMM ---------------------------
__global__ __launch_bounds__(256, 2)
void oproj_kernel(const short* __restrict__ A, const float* __restrict__ W,
                  const float* __restrict__ bias, float* __restrict__ out) {
  __shared__ short As[128 * 32], Bs[128 * 32];
  const int m0 = blockIdx.x * 128, n0 = blockIdx.y * 128;
  const int t = threadIdx.x, lane = t & 63, w = t >> 6;
  const int wr = w >> 1, wc = w & 1;
  const int fr = lane & 15, fg = lane >> 4;

  f32x4 acc[4][4];
#pragma unroll
  for (int a = 0; a < 4; ++a)
#pragma unroll
    for (int b = 0; b < 4; ++b) acc[a][b] = f32x4{0.f, 0.f, 0.f, 0.f};

  for (int kt = 0; kt < 16; ++kt) {
    __syncthreads();
#pragma unroll
    for (int cc = 0; cc < 2; ++cc) {
      int cid = t + cc * 256;
      int row = cid >> 2, kb = cid & 3;
      ((s16x8*)As)[cid] =
          *(const s16x8*)(A + (size_t)(m0 + row) * DM_ + kt * 32 + kb * 8);
      const float* gb = W + (size_t)(n0 + row) * DM_ + kt * 32 + kb * 8;
      float fb[8];
      *(f32x4*)&fb[0] = *(const f32x4*)gb;  *(f32x4*)&fb[4] = *(const f32x4*)(gb + 4);
      s16x8 hb;
#pragma unroll
      for (int j = 0; j < 8; ++j) hb[j] = f2bf(fb[j]);
      ((s16x8*)Bs)[cid] = hb;
    }
    __syncthreads();
    s16x8 af[4], bf[4];
#pragma unroll
    for (int fm = 0; fm < 4; ++fm)
      af[fm] = ((const s16x8*)As)[(wr * 64 + fm * 16 + fr) * 4 + fg];
#pragma unroll
    for (int fn = 0; fn < 4; ++fn)
      bf[fn] = ((const s16x8*)Bs)[(wc * 64 + fn * 16 + fr) * 4 + fg];
#pragma unroll
    for (int fm = 0; fm < 4; ++fm)
#pragma unroll
      for (int fn = 0; fn < 4; ++fn) acc[fm][fn] = mfma16(af[fm], bf[fn], acc[fm][fn]);
  }
#pragma unroll
  for (int fn = 0; fn < 4; ++fn) {
    int C = n0 + wc * 64 + fn * 16 + fr;
    float bb = bias[C];
#pragma unroll
    for (int fm = 0; fm < 4; ++fm) {
      int Rbase = m0 + wr * 64 + fm * 16 + fg * 4;
#pragma unroll
      for (int i = 0; i < 4; ++i)
        out[(size_t)(Rbase + i) * DM_ + C] = acc[fm][fn][i] + bb;
    }
  }
}

// ---------------------------------------------------------------------------
extern "C" void kernel_launch(void* const* d_in, const int* in_sizes, int n_in,
                              void* d_out, int out_size, void* d_ws, size_t ws_size,
                              hipStream_t stream) {
  const float* Qin = (const float*)d_in[0];
  const float* Kin = (const float*)d_in[1];
  const float* Vin = (const float*)d_in[2];
  const float* Wq  = (const float*)d_in[3];
  const float* bq  = (const float*)d_in[4];
  const float* Wk  = (const float*)d_in[5];
  const float* bk  = (const float*)d_in[6];
  const float* Wv  = (const float*)d_in[7];
  const float* bv  = (const float*)d_in[8];
  const float* Wo  = (const float*)d_in[9];
  const float* bo  = (const float*)d_in[10];
  const float* lw  = (const float*)d_in[11];

  char* ws = (char*)d_ws;
  const size_t SZ = (size_t)NB_ * NH_ * L_ * DK_ * 2;  // 8 MiB per bf16 buffer
  short* Qh = (short*)(ws);
  short* Ql = (short*)(ws + SZ);
  short* Kh = (short*)(ws + 2 * SZ);
  short* Kl = (short*)(ws + 3 * SZ);
  short* Vt = (short*)(ws + 4 * SZ);
  short* heads = (short*)(ws + 5 * SZ);
  float* ctab = (float*)(ws + 6 * SZ);
  float* stab = ctab + NH_ * L_;

  float* out  = (float*)d_out;                       // [4,2048,512]
  float* attn = out + (size_t)NB_ * L_ * DM_;        // [4,8,2048,2048]

  tab_kernel<<<dim3(L_ / 256, NH_), 256, 0, stream>>>(lw, ctab, stab);
  proj_kernel<<<dim3(64, 4, 3), 256, 0, stream>>>(Qin, Kin, Vin, Wq, bq, Wk, bk,
                                                  Wv, bv, Qh, Ql, Kh, Kl, Vt);
  attn_kernel<<<dim3(L_ / 16, NB_ * NH_), 512, 0, stream>>>(Qh, Ql, Kh, Kl, Vt,
                                                            ctab, stab, attn, heads);
  oproj_kernel<<<dim3(64, 4), 256, 0, stream>>>(heads, Wo, bo, out);
}